// Round 4
// baseline (2278.629 us; speedup 1.0000x reference)
//
#include <hip/hip_runtime.h>
#include <hip/hip_bf16.h>
#include <math.h>

typedef short short8 __attribute__((ext_vector_type(8)));
typedef short short4v __attribute__((ext_vector_type(4)));
typedef float floatx4 __attribute__((ext_vector_type(4)));

#define DEV static __device__ __forceinline__

DEV float s2f(short v) {
    unsigned int u = ((unsigned int)(unsigned short)v) << 16;
    float f;
    __builtin_memcpy(&f, &u, 4);
    return f;
}
DEV short f2s(float f) {
    __hip_bfloat16 b = __float2bfloat16(f);   // RNE
    short s;
    __builtin_memcpy(&s, &b, 2);
    return s;
}

DEV void async_copy16(const void* g, void* l) {
    __builtin_amdgcn_global_load_lds(
        (const __attribute__((address_space(1))) void*)g,
        (__attribute__((address_space(3))) void*)l, 16, 0, 0);
}

// m204 bijective XCD-chunk transform: contiguous pos ranges land on one XCD
// (hardware round-robins blockIdx.x % 8 across the 8 XCDs).
DEV int xcd_chunk(int id, int n) {
    const int q = n >> 3, r = n & 7;
    const int x = id & 7, j = id >> 3;
    return (x < r ? x * (q + 1) : r * (q + 1) + (x - r) * q) + j;
}

struct GP {
    const short* A;  long long zA; int lda;
    const short* Bt; long long zB; int ldb;
    const float* bias;
    const short* R;  int ldr;
    short* C;        long long zC; int ldc;
    int M, N, K;
};

// ---------------------------------------------------------------------------
// gemm64: 64(M)x128(N) tile, BK=64 as two 32-k panels (legacy path for
// small/odd grids: patch embed, S=QK^T).
// ---------------------------------------------------------------------------
template<int EPI>
DEV void gemm_body(short* smem, const GP p, int bx, int by, int bz)
{
    const short* A  = p.A  + (long long)bz * p.zA;
    const short* Bt = p.Bt + (long long)bz * p.zB;
    short* C        = p.C  + (long long)bz * p.zC;

    const int tid   = threadIdx.x;
    const int lane  = tid & 63;
    const int wave  = tid >> 6;
    const int tileM = bx * 64;
    const int tileN = by * 128;
    const int wm    = (wave & 1) * 32;
    const int wn    = (wave >> 1) * 64;

    floatx4 acc[2][4];
#pragma unroll
    for (int mt = 0; mt < 2; ++mt)
#pragma unroll
        for (int nt = 0; nt < 4; ++nt)
            acc[mt][nt] = (floatx4){0.f, 0.f, 0.f, 0.f};

    for (int k0 = 0; k0 < p.K; k0 += 64) {
#pragma unroll
        for (int h = 0; h < 2; ++h) {
            {   // A panel 64x32: 256 16B chunks, 1/thread
                const int c   = tid;
                const int row = c >> 2;
                const int ko  = (c & 3) * 8;
                async_copy16(A + (long long)(tileM + row) * p.lda + k0 + h * 32 + ko,
                             &smem[h * 2048 + c * 8]);
            }
#pragma unroll
            for (int i = 0; i < 2; ++i) {   // B panel 128x32: 512 chunks, 2/thread
                const int c   = i * 256 + tid;
                const int row = c >> 2;
                const int ko  = (c & 3) * 8;
                async_copy16(Bt + (long long)(tileN + row) * p.ldb + k0 + h * 32 + ko,
                             &smem[4096 + h * 4096 + c * 8]);
            }
        }
        __syncthreads();

        const int fr = lane & 15;
        const int ko = (lane >> 4) * 8;
#pragma unroll
        for (int h = 0; h < 2; ++h) {
            const short* pA = &smem[h * 2048];
            const short* pB = &smem[4096 + h * 4096];
            short8 af[2], bf[4];
#pragma unroll
            for (int t = 0; t < 2; ++t)
                af[t] = *(const short8*)&pA[(wm + fr + t * 16) * 32 + ko];
#pragma unroll
            for (int t = 0; t < 4; ++t)
                bf[t] = *(const short8*)&pB[(wn + fr + t * 16) * 32 + ko];
#pragma unroll
            for (int mt = 0; mt < 2; ++mt)
#pragma unroll
                for (int nt = 0; nt < 4; ++nt)
                    acc[mt][nt] = __builtin_amdgcn_mfma_f32_16x16x32_bf16(
                        af[mt], bf[nt], acc[mt][nt], 0, 0, 0);
        }
        __syncthreads();
    }

    float* eps = (float*)smem + wave * (16 * 68);
    const int col = lane & 15;
    const int rb  = (lane >> 4) * 4;
#pragma unroll
    for (int mt = 0; mt < 2; ++mt) {
        const int gr0 = tileM + wm + mt * 16;
        const int gc0 = tileN + wn;
#pragma unroll
        for (int nt = 0; nt < 4; ++nt) {
            float bv = 0.0f;
            if constexpr (EPI != 3) { if (p.bias) bv = p.bias[gc0 + nt * 16 + col]; }
#pragma unroll
            for (int r = 0; r < 4; ++r) {
                float v = acc[mt][nt][r] + bv;
                if constexpr (EPI == 1) v = 0.5f * v * (1.0f + erff(v * 0.70710678118654752f));
                eps[(rb + r) * 68 + nt * 16 + col] = v;
            }
        }
#pragma unroll
        for (int j = 0; j < 2; ++j) {
            const int r  = (lane >> 3) + 8 * j;
            const int cb = (lane & 7) * 8;
            const floatx4 f0 = *(const floatx4*)&eps[r * 68 + cb];
            const floatx4 f1 = *(const floatx4*)&eps[r * 68 + cb + 4];
            const int gr = gr0 + r;
            if (gr >= p.M) continue;
            float rbv = 0.0f;
            if constexpr (EPI == 3) rbv = p.bias[gr];
            short8 o;
            if constexpr (EPI == 2) {
                const short8 rr = *(const short8*)&p.R[(long long)gr * p.ldr + gc0 + cb];
#pragma unroll
                for (int i = 0; i < 4; ++i) {
                    o[i]     = f2s(f0[i] + s2f(rr[i]));
                    o[4 + i] = f2s(f1[i] + s2f(rr[4 + i]));
                }
            } else {
#pragma unroll
                for (int i = 0; i < 4; ++i) {
                    o[i]     = f2s(f0[i] + rbv);
                    o[4 + i] = f2s(f1[i] + rbv);
                }
            }
            *(short8*)&C[(long long)gr * p.ldc + gc0 + cb] = o;
        }
    }
}

template<int EPI>
__global__ __launch_bounds__(256) void gemm64_k(GP p)
{
    __shared__ short smem[12288];
    gemm_body<EPI>(smem, p, blockIdx.x, blockIdx.y, blockIdx.z);
}

// ---------------------------------------------------------------------------
// gemm128: 128x128 tile, BK=32, double-buffered prefetch (T3 minimum-2-phase:
// issue next-tile global_load_lds BEFORE ds_read+MFMA, ONE barrier per step).
// LDS = 2 x 16 KB = 32 KB -> 5 blocks/CU cap (was 64 KB / 2 blocks). With 984-
// and 300-block grids fully co-resident, inter-block stagger hides the load
// round trip (G1 / m97 mechanism).
// 4-slot XOR swizzle (slot ^= row&3) on global source + ds_read addr (rule
// #21 involution): 8-way -> 4-way bank spread on ds_read_b128.
// 4 waves in 2x2, each 64x64 (4x4 frags of 16x16x32).
// ---------------------------------------------------------------------------
template<int EPI>
DEV void gemm128_body(short* smem, const GP p, int bx, int by, int bz)
{
    const short* A  = p.A  + (long long)bz * p.zA;
    const short* Bt = p.Bt + (long long)bz * p.zB;
    short* C        = p.C  + (long long)bz * p.zC;

    const int tid   = threadIdx.x;
    const int lane  = tid & 63;
    const int wave  = tid >> 6;
    const int tileM = bx * 128;
    const int tileN = by * 128;
    const int wm    = (wave & 1) * 64;
    const int wn    = (wave >> 1) * 64;

    floatx4 acc[4][4];
#pragma unroll
    for (int mt = 0; mt < 4; ++mt)
#pragma unroll
        for (int nt = 0; nt < 4; ++nt)
            acc[mt][nt] = (floatx4){0.f, 0.f, 0.f, 0.f};

    // staging: per buffer 8192 shorts (A [0,4096), B [4096,8192)).
    // thread tid handles chunks c = i*256+tid, row = c>>2 = i*64 + (tid>>2),
    // LDS slot sL = c&3 = tid&3; global slot sG = sL ^ (row&3), row&3 =
    // (tid>>2)&3 invariant across i (64 = 0 mod 4) -> thread-constant source.
    const int arow = tid >> 2;
    const int asl  = ((tid & 3) ^ (arow & 3)) * 8;
    const short* gA = A  + (long long)(tileM + arow) * p.lda + asl;
    const short* gB = Bt + (long long)(tileN + arow) * p.ldb + asl;
    const long long stA = 64LL * p.lda;
    const long long stB = 64LL * p.ldb;

    auto stage = [&](int buf, int k0) {
        short* dst = smem + buf * 8192;
#pragma unroll
        for (int i = 0; i < 2; ++i)
            async_copy16(gA + i * stA + k0, &dst[(i * 256 + tid) * 8]);
#pragma unroll
        for (int i = 0; i < 2; ++i)
            async_copy16(gB + i * stB + k0, &dst[4096 + (i * 256 + tid) * 8]);
    };

    const int nK = p.K >> 5;
    stage(0, 0);
    __syncthreads();

    const int fr = lane & 15;
    const int q  = lane >> 4;              // 0..3: k-quarter slot
    for (int ks = 0; ks < nK; ++ks) {
        if (ks + 1 < nK) stage((ks + 1) & 1, (ks + 1) << 5);   // prefetch overlaps compute
        const short* pA = smem + (ks & 1) * 8192;
        const short* pB = pA + 4096;
        short8 af[4], bf[4];
#pragma unroll
        for (int t = 0; t < 4; ++t) {
            const int row = wm + t * 16 + fr;
            af[t] = *(const short8*)&pA[row * 32 + ((q ^ (row & 3)) * 8)];
        }
#pragma unroll
        for (int t = 0; t < 4; ++t) {
            const int row = wn + t * 16 + fr;
            bf[t] = *(const short8*)&pB[row * 32 + ((q ^ (row & 3)) * 8)];
        }
#pragma unroll
        for (int mt = 0; mt < 4; ++mt)
#pragma unroll
            for (int nt = 0; nt < 4; ++nt)
                acc[mt][nt] = __builtin_amdgcn_mfma_f32_16x16x32_bf16(
                    af[mt], bf[nt], acc[mt][nt], 0, 0, 0);
        __syncthreads();   // drains prefetch (vmcnt 0) + readers done -> swap safe
    }

    // ---- epilogue: wave-private fp32 LDS stage -> coalesced short8 stores ----
    float* eps = (float*)smem + wave * (16 * 68);
    const int col = lane & 15;
    const int rb  = (lane >> 4) * 4;
#pragma unroll
    for (int mt = 0; mt < 4; ++mt) {
        const int gr0 = tileM + wm + mt * 16;
        const int gc0 = tileN + wn;
#pragma unroll
        for (int nt = 0; nt < 4; ++nt) {
            float bv = 0.0f;
            if constexpr (EPI != 3) { if (p.bias) bv = p.bias[gc0 + nt * 16 + col]; }
#pragma unroll
            for (int r = 0; r < 4; ++r) {
                float v = acc[mt][nt][r] + bv;
                if constexpr (EPI == 1) v = 0.5f * v * (1.0f + erff(v * 0.70710678118654752f));
                eps[(rb + r) * 68 + nt * 16 + col] = v;
            }
        }
        // wave-private region; DS ops in-order per wave — no barrier needed
#pragma unroll
        for (int j = 0; j < 2; ++j) {
            const int r  = (lane >> 3) + 8 * j;
            const int cb = (lane & 7) * 8;
            const floatx4 f0 = *(const floatx4*)&eps[r * 68 + cb];
            const floatx4 f1 = *(const floatx4*)&eps[r * 68 + cb + 4];
            const int gr = gr0 + r;
            if (gr >= p.M) continue;
            float rbv = 0.0f;
            if constexpr (EPI == 3) rbv = p.bias[gr];
            short8 o;
            if constexpr (EPI == 2) {
                const short8 rr = *(const short8*)&p.R[(long long)gr * p.ldr + gc0 + cb];
#pragma unroll
                for (int i = 0; i < 4; ++i) {
                    o[i]     = f2s(f0[i] + s2f(rr[i]));
                    o[4 + i] = f2s(f1[i] + s2f(rr[4 + i]));
                }
            } else {
#pragma unroll
                for (int i = 0; i < 4; ++i) {
                    o[i]     = f2s(f0[i] + rbv);
                    o[4 + i] = f2s(f1[i] + rbv);
                }
            }
            *(short8*)&C[(long long)gr * p.ldc + gc0 + cb] = o;
        }
    }
}

// flat-grid gemm128 with XCD-chunked, by-fast decode:
// pos = z*perZ + bx*nBy + by  (same-bx contiguous -> A-panel L2 reuse per XCD)
template<int EPI>
__global__ __launch_bounds__(256) void gemm128f_k(GP p, int nBy, int perZ)
{
    __shared__ short smem[16384];
    const int pos = xcd_chunk((int)blockIdx.x, (int)gridDim.x);
    const int z   = pos / perZ;
    const int rem = pos % perZ;
    gemm128_body<EPI>(smem, p, rem / nBy, rem % nBy, z);
}

// Combined QK (EPI 0) + VT (EPI 3) dispatch: flat grid, chunked, block branch.
// QK: 50 bx x 12 by (by-fast). VT: 32 z x 6 bx x 2 by (z-major).
__global__ __launch_bounds__(256) void qkvt_k(GP qk, GP vt, int nQK)
{
    __shared__ short smem[16384];
    const int pos = xcd_chunk((int)blockIdx.x, (int)gridDim.x);
    if (pos < nQK) {
        gemm128_body<0>(smem, qk, pos / 12, pos % 12, 0);
    } else {
        const int i2 = pos - nQK;
        gemm128_body<3>(smem, vt, (i2 % 12) >> 1, i2 & 1, i2 / 12);
    }
}

// ---------------------------------------------------------------------------
// Transpose-convert: out_bf16[z][n][k] = f2s(in_f32[z][k][n]). K,N mult of 32.
// ---------------------------------------------------------------------------
__global__ void tconv_k(const float* __restrict__ in, short* __restrict__ out,
                        int K, int N, long long inZ, long long outZ)
{
    __shared__ float t[32][33];
    in  += (long long)blockIdx.z * inZ;
    out += (long long)blockIdx.z * outZ;
    const int n0 = blockIdx.x * 32, k0 = blockIdx.y * 32;
    const int tx = threadIdx.x, ty = threadIdx.y;
#pragma unroll
    for (int i = 0; i < 4; ++i)
        t[ty + i * 8][tx] = in[(long long)(k0 + ty + i * 8) * N + n0 + tx];
    __syncthreads();
#pragma unroll
    for (int i = 0; i < 4; ++i)
        out[(long long)(n0 + ty + i * 8) * K + k0 + tx] = f2s(t[tx][ty + i * 8]);
}

// x fp32 -> bf16, 4 elems/thread (G13)
__global__ __launch_bounds__(256) void cvtx4_k(const float* __restrict__ x,
                                               short* __restrict__ xb, int n4)
{
    const int i = blockIdx.x * 256 + threadIdx.x;
    if (i >= n4) return;
    const floatx4 v = *(const floatx4*)&x[i * 4];
    short4v o;
#pragma unroll
    for (int e = 0; e < 4; ++e) o[e] = f2s(v[e]);
    *(short4v*)&xb[i * 4] = o;
}

// concat per-layer q/k biases -> [12][1536] fp32
__global__ __launch_bounds__(256) void bqk_k(
    const float* __restrict__ bq, const float* __restrict__ bk,
    float* __restrict__ out)
{
    const int i = blockIdx.x * 256 + threadIdx.x;
    if (i >= 12 * 1536) return;
    const int l = i / 1536, j = i % 1536;
    out[i] = (j < 768) ? bq[l * 768 + j] : bk[l * 768 + j - 768];
}

// ---------------------------------------------------------------------------
// assemble: H[b][t][d] = (t==0 ? cls[d] : P[b*196+t-1][d]) + pos[t][d]
// 4 elems/thread (d-contiguous; t uniform within a chunk).
// ---------------------------------------------------------------------------
__global__ __launch_bounds__(256) void assemble4_k(
    const short* __restrict__ P, const float* __restrict__ cls,
    const float* __restrict__ pos, short* __restrict__ H)
{
    const int c = blockIdx.x * 256 + threadIdx.x;   // chunk of 4; 32*197*192 total
    if (c >= 32 * 197 * 192) return;
    const int d4 = c % 192;
    const int t  = (c / 192) % 197;
    const long long b = c / (192 * 197);
    const floatx4 pv = *(const floatx4*)&pos[t * 768 + d4 * 4];
    float o[4];
    if (t == 0) {
        const floatx4 cv = *(const floatx4*)&cls[d4 * 4];
#pragma unroll
        for (int e = 0; e < 4; ++e) o[e] = cv[e] + pv[e];
    } else {
        const short4v pc = *(const short4v*)&P[(b * 196 + t - 1) * 768 + d4 * 4];
#pragma unroll
        for (int e = 0; e < 4; ++e) o[e] = s2f(pc[e]) + pv[e];
    }
    short4v ov;
#pragma unroll
    for (int e = 0; e < 4; ++e) ov[e] = f2s(o[e]);
    *(short4v*)&H[((b * 197 + t) * 768) + d4 * 4] = ov;
}

// ---------------------------------------------------------------------------
// wave-per-row softmax on padded S (4 rows/block, 1576 blocks).
// Row r = b*197+t lives at S[(b*256+t)*256]. Lane loads cols [4*lane,4*lane+4):
// one short4, masks cols >= 197, shuffle-reduce max+sum, writes full 256 cols
// (pad cols = 0 so PV's K=256 pad stays exact).
// ---------------------------------------------------------------------------
__global__ __launch_bounds__(256) void softmaxw_k(short* __restrict__ S, float scale)
{
    const int row  = blockIdx.x * 4 + (threadIdx.x >> 6);
    const int lane = threadIdx.x & 63;
    if (row >= 32 * 197) return;
    const int b = row / 197, t = row % 197;
    short* s = S + ((long long)b * 256 + t) * 256;
    const int c0 = lane * 4;

    const short4v v = *(const short4v*)&s[c0];
    float f[4], mx = -1e30f;
#pragma unroll
    for (int e = 0; e < 4; ++e) {
        f[e] = (c0 + e < 197) ? s2f(v[e]) * scale : -1e30f;
        mx = fmaxf(mx, f[e]);
    }
#pragma unroll
    for (int m = 1; m < 64; m <<= 1) mx = fmaxf(mx, __shfl_xor(mx, m, 64));
    float e4[4], sum = 0.0f;
#pragma unroll
    for (int e = 0; e < 4; ++e) {
        e4[e] = (c0 + e < 197) ? expf(f[e] - mx) : 0.0f;
        sum += e4[e];
    }
#pragma unroll
    for (int m = 1; m < 64; m <<= 1) sum += __shfl_xor(sum, m, 64);
    const float inv = 1.0f / sum;
    short4v o;
#pragma unroll
    for (int e = 0; e < 4; ++e) o[e] = f2s(e4[e] * inv);
    *(short4v*)&s[c0] = o;
}

// ---------------------------------------------------------------------------
// wave-per-row LayerNorm over 768 (shuffle reduce). 4 rows/block.
// Vectorized: 3 x short4 loads / stores per lane (G13).
// ---------------------------------------------------------------------------
__global__ __launch_bounds__(256) void lnw_k(
    const short* __restrict__ X, long long xs,
    short* __restrict__ Y, long long ys,
    const float* __restrict__ g, const float* __restrict__ be, int nrows)
{
    const int row  = blockIdx.x * 4 + (threadIdx.x >> 6);
    const int lane = threadIdx.x & 63;
    if (row >= nrows) return;
    const short* x = X + (long long)row * xs;
    short* y = Y + (long long)row * ys;

    float v[12], s = 0.0f, sq = 0.0f;
#pragma unroll
    for (int j = 0; j < 3; ++j) {
        const short4v t4 = *(const short4v*)&x[(lane + 64 * j) * 4];
#pragma unroll
        for (int e = 0; e < 4; ++e) {
            const float t = s2f(t4[e]);
            v[j * 4 + e] = t; s += t; sq += t * t;
        }
    }
#pragma unroll
    for (int m = 1; m < 64; m <<= 1) {
        s  += __shfl_xor(s,  m, 64);
        sq += __shfl_xor(sq, m, 64);
    }
    const float mean = s * (1.0f / 768.0f);
    const float var  = sq * (1.0f / 768.0f) - mean * mean;
    const float rs   = rsqrtf(var + 1e-5f);
#pragma unroll
    for (int j = 0; j < 3; ++j) {
        const int d0 = (lane + 64 * j) * 4;
        const floatx4 gv = *(const floatx4*)&g[d0];
        const floatx4 bv = *(const floatx4*)&be[d0];
        short4v o;
#pragma unroll
        for (int e = 0; e < 4; ++e)
            o[e] = f2s((v[j * 4 + e] - mean) * rs * gv[e] + bv[e]);
        *(short4v*)&y[d0] = o;
    }
}

// ---------------------------------------------------------------------------
// head3: out[b][c] = hc[b].W[:,c] + hb[c]; split-k x4 + LDS reduce.
// grid (16, 32); block 256 = 64 cols x 4 k-slices. fp32 W, fp32 out.
// ---------------------------------------------------------------------------
__global__ __launch_bounds__(256) void head3_k(
    const short* __restrict__ hc, const float* __restrict__ W,
    const float* __restrict__ hb, float* __restrict__ out)
{
    const int b  = blockIdx.y;
    const int cc = threadIdx.x & 63;
    const int ks = threadIdx.x >> 6;
    const int c  = blockIdx.x * 64 + cc;
    __shared__ float h[768];
    __shared__ float red[4][64];
    for (int i = threadIdx.x; i < 768; i += 256) h[i] = s2f(hc[b * 768 + i]);
    __syncthreads();
    float acc = 0.0f;
    if (c < 1000) {
        const int k0 = ks * 192;
        for (int k = k0; k < k0 + 192; ++k) acc += h[k] * W[k * 1000 + c];
    }
    red[ks][cc] = acc;
    __syncthreads();
    if (ks == 0 && c < 1000)
        out[b * 1000 + c] = red[0][cc] + red[1][cc] + red[2][cc] + red[3][cc] + hb[c];
}

// ---------------------------------------------------------------------------
extern "C" void kernel_launch(void* const* d_in, const int* in_sizes, int n_in,
                              void* d_out, int out_size, void* d_ws, size_t ws_size,
                              hipStream_t stream)
{
    const float* x     = (const float*)d_in[0];
    const float* cls   = (const float*)d_in[1];
    const float* emb_w = (const float*)d_in[2];
    const float* emb_b = (const float*)d_in[3];
    const float* pos   = (const float*)d_in[4];
    const float* Wq    = (const float*)d_in[5];
    const float* bq    = (const float*)d_in[6];
    const float* Wk    = (const float*)d_in[7];
    const float* bk    = (const float*)d_in[8];
    const float* Wv    = (const float*)d_in[9];
    const float* bv    = (const float*)d_in[10];
    const float* Wo    = (const float*)d_in[11];
    const float* bo    = (const float*)d_in[12];
    const float* g1    = (const float*)d_in[13];
    const float* be1   = (const float*)d_in[14];
    const float* W1    = (const float*)d_in[15];
    const float* b1    = (const float*)d_in[16];
    const float* W2    = (const float*)d_in[17];
    const float* b2    = (const float*)d_in[18];
    const float* g2    = (const float*)d_in[19];
    const float* be2   = (const float*)d_in[20];
    const float* fg    = (const float*)d_in[21];
    const float* fb    = (const float*)d_in[22];
    const float* hw    = (const float*)d_in[23];
    const float* hb    = (const float*)d_in[24];

    char* ws = (char*)d_ws;
    long long o = 0;
    short* WtQK = (short*)(ws + o); o += 12LL * 1536 * 768 * 2;
    short* WtV  = (short*)(ws + o); o += 12LL * 768 * 768 * 2;
    short* WtO  = (short*)(ws + o); o += 12LL * 768 * 768 * 2;
    short* Wt1  = (short*)(ws + o); o += 12LL * 768 * 768 * 2;
    short* Wt2  = (short*)(ws + o); o += 12LL * 768 * 768 * 2;
    short* embT = (short*)(ws + o); o += 768LL * 256 * 2;
    short* H    = (short*)(ws + o); o += 6400LL * 768 * 2;
    short* QKVb = (short*)(ws + o); o += 6400LL * 1536 * 2;
    short* AO   = (short*)(ws + o); o += 6400LL * 768 * 2;
    short* VT   = (short*)(ws + o); o += 32LL * 768 * 256 * 2;
    short* T1   = VT;                                  // alias (disjoint in time)
    short* S    = (short*)(ws + o); o += 32LL * 256 * 256 * 2;
    short* xb   = S;                                   // alias (disjoint in time)
    short* hc   = (short*)(ws + o); o += 64LL * 768 * 2;
    float* bqk  = (float*)(ws + o); o += 12LL * 1536 * 4;

    const dim3 blk(256);
    const dim3 tblk(32, 8);
    const float scale = 0.03608439182435161f;  // 768^-0.5
    const long long sH  = 197LL * 768;
    const long long sQK = 197LL * 1536;
    const long long sS  = 256LL * 256;
    const long long sVT = 768LL * 256;

    // ---- prep ----
    tconv_k<<<dim3(24, 8, 1),   tblk, 0, stream>>>(emb_w, embT, 256, 768, 0, 0);
    tconv_k<<<dim3(24, 24, 12), tblk, 0, stream>>>(Wq, WtQK,             768, 768, 589824, 1536LL * 768);
    tconv_k<<<dim3(24, 24, 12), tblk, 0, stream>>>(Wk, WtQK + 768 * 768, 768, 768, 589824, 1536LL * 768);
    tconv_k<<<dim3(24, 24, 12), tblk, 0, stream>>>(Wv, WtV, 768, 768, 589824, 589824);
    tconv_k<<<dim3(24, 24, 12), tblk, 0, stream>>>(Wo, WtO, 768, 768, 589824, 589824);
    tconv_k<<<dim3(24, 24, 12), tblk, 0, stream>>>(W1, Wt1, 768, 768, 589824, 589824);
    tconv_k<<<dim3(24, 24, 12), tblk, 0, stream>>>(W2, Wt2, 768, 768, 589824, 589824);
    cvtx4_k<<<dim3(1568), blk, 0, stream>>>(x, xb, 6272 * 64);
    bqk_k<<<dim3(72), blk, 0, stream>>>(bq, bk, bqk);

    // ---- patch embed + assemble (gemm64: 98x6 grid fills the machine better) ----
    {
        GP p = { xb, 0, 256, embT, 0, 256, emb_b, nullptr, 0, T1, 0, 768, 6272, 768, 256 };
        gemm64_k<0><<<dim3(98, 6), blk, 0, stream>>>(p);
    }
    assemble4_k<<<dim3((32 * 197 * 192 + 255) / 256), blk, 0, stream>>>(T1, cls, pos, H);

    for (int l = 0; l < 12; ++l) {
        const long long w1o = (long long)l * 589824;
        const long long vo  = (long long)l * 768;
        // QK [6304][1536] (50x12 @128^2) + VT[b][d][t] (32x6x2) in ONE dispatch
        {
            GP qk = { H, 0, 768, WtQK + (long long)l * 1536 * 768, 0, 768,
                      bqk + l * 1536, nullptr, 0, QKVb, 0, 1536, 6304, 1536, 768 };
            GP vt = { WtV + w1o, 0, 768, H, sH, 768, bv + vo,
                      nullptr, 0, VT, sVT, 256, 768, 256, 768 };
            qkvt_k<<<dim3(600 + 384), blk, 0, stream>>>(qk, vt, 600);
        }
        // S[b] = Q[b] @ K[b]^T  [197(pad256)][256]  (small: keep gemm64)
        {
            GP p = { QKVb, sQK, 1536, QKVb + 768, sQK, 1536, nullptr,
                     nullptr, 0, S, sS, 256, 197, 256, 768 };
            gemm64_k<0><<<dim3(4, 2, 32), blk, 0, stream>>>(p);
        }
        softmaxw_k<<<dim3(1576), blk, 0, stream>>>(S, scale);
        // AO[b] = P[b] @ VT[b]^T   (K=256; pad cols of P are 0); 32z x 2bx x 6by
        {
            GP p = { S, sS, 256, VT, sVT, 256, nullptr,
                     nullptr, 0, AO, sH, 768, 197, 768, 256 };
            gemm128f_k<0><<<dim3(384), blk, 0, stream>>>(p, 6, 12);
        }
        // T1 = AO @ Wo + bo + H ; H = LN(T1)   (50bx x 6by, by-fast chunked)
        {
            GP p = { AO, 0, 768, WtO + w1o, 0, 768, bo + vo, H, 768,
                     T1, 0, 768, 6304, 768, 768 };
            gemm128f_k<2><<<dim3(300), blk, 0, stream>>>(p, 6, 300);
        }
        lnw_k<<<dim3(1576), blk, 0, stream>>>(T1, 768, H, 768, g1 + vo, be1 + vo, 6304);
        // T1 = gelu(H @ W1 + b1) ; AO = T1 @ W2 + b2 + H ; H = LN(AO)
        {
            GP p = { H, 0, 768, Wt1 + w1o, 0, 768, b1 + vo, nullptr, 0,
                     T1, 0, 768, 6304, 768, 768 };
            gemm128f_k<1><<<dim3(300), blk, 0, stream>>>(p, 6, 300);
        }
        {
            GP p = { T1, 0, 768, Wt2 + w1o, 0, 768, b2 + vo, H, 768,
                     AO, 0, 768, 6304, 768, 768 };
            gemm128f_k<2><<<dim3(300), blk, 0, stream>>>(p, 6, 300);
        }
        lnw_k<<<dim3(1576), blk, 0, stream>>>(AO, 768, H, 768, g2 + vo, be2 + vo, 6304);
    }

    // final LN on cls tokens (stride 197*768) + head
    lnw_k<<<dim3(8), blk, 0, stream>>>(H, sH, hc, 768, fg, fb, 32);
    head3_k<<<dim3(16, 32), blk, 0, stream>>>(hc, hw, hb, (float*)d_out);
}

// Round 6
// 1876.615 us; speedup vs baseline: 1.2142x; 1.2142x over previous
//
#include <hip/hip_runtime.h>
#include <hip/hip_bf16.h>
#include <math.h>

typedef short short8 __attribute__((ext_vector_type(8)));
typedef short short4v __attribute__((ext_vector_type(4)));
typedef float floatx4 __attribute__((ext_vector_type(4)));

#define DEV static __device__ __forceinline__

DEV float s2f(short v) {
    unsigned int u = ((unsigned int)(unsigned short)v) << 16;
    float f;
    __builtin_memcpy(&f, &u, 4);
    return f;
}
DEV short f2s(float f) {
    __hip_bfloat16 b = __float2bfloat16(f);   // RNE
    short s;
    __builtin_memcpy(&s, &b, 2);
    return s;
}

DEV void async_copy16(const void* g, void* l) {
    __builtin_amdgcn_global_load_lds(
        (const __attribute__((address_space(1))) void*)g,
        (__attribute__((address_space(3))) void*)l, 16, 0, 0);
}

// m204 bijective XCD-chunk transform: contiguous pos ranges land on one XCD
// (hardware round-robins blockIdx.x % 8 across the 8 XCDs).
DEV int xcd_chunk(int id, int n) {
    const int q = n >> 3, r = n & 7;
    const int x = id & 7, j = id >> 3;
    return (x < r ? x * (q + 1) : r * (q + 1) + (x - r) * q) + j;
}

struct GP {
    const short* A;  long long zA; int lda;
    const short* Bt; long long zB; int ldb;
    const float* bias;
    const short* R;  int ldr;
    short* C;        long long zC; int ldc;
    int M, N, K;
};

// ---------------------------------------------------------------------------
// gemm128: 128x128 tile, BK=64, double-buffered prefetch (round-3 version,
// verbatim — measured 40.4 us on qkvt). 8-slot XOR swizzle (row&7) on global
// source + ds_read addr (rule #21 involution). 64 KB LDS, 2 blk/CU.
// ---------------------------------------------------------------------------
template<int EPI>
DEV void gemm128_body(short* smem, const GP p, int bx, int by, int bz)
{
    const short* A  = p.A  + (long long)bz * p.zA;
    const short* Bt = p.Bt + (long long)bz * p.zB;
    short* C        = p.C  + (long long)bz * p.zC;

    const int tid   = threadIdx.x;
    const int lane  = tid & 63;
    const int wave  = tid >> 6;
    const int tileM = bx * 128;
    const int tileN = by * 128;
    const int wm    = (wave & 1) * 64;
    const int wn    = (wave >> 1) * 64;

    floatx4 acc[4][4];
#pragma unroll
    for (int mt = 0; mt < 4; ++mt)
#pragma unroll
        for (int nt = 0; nt < 4; ++nt)
            acc[mt][nt] = (floatx4){0.f, 0.f, 0.f, 0.f};

    const int arow = tid >> 3;
    const int asl  = ((tid & 7) ^ (arow & 7)) * 8;
    const short* gA = A  + (long long)(tileM + arow) * p.lda + asl;
    const short* gB = Bt + (long long)(tileN + arow) * p.ldb + asl;
    const long long stA = 32LL * p.lda;
    const long long stB = 32LL * p.ldb;

    auto stage = [&](int buf, int k0) {
        short* dst = smem + buf * 16384;
#pragma unroll
        for (int i = 0; i < 4; ++i)
            async_copy16(gA + i * stA + k0, &dst[(i * 256 + tid) * 8]);
#pragma unroll
        for (int i = 0; i < 4; ++i)
            async_copy16(gB + i * stB + k0, &dst[8192 + (i * 256 + tid) * 8]);
    };

    const int nK = p.K >> 6;
    stage(0, 0);
    __syncthreads();

    const int fr = lane & 15;
    const int q  = lane >> 4;
    for (int ks = 0; ks < nK; ++ks) {
        if (ks + 1 < nK) stage((ks + 1) & 1, (ks + 1) << 6);   // prefetch overlaps compute
        const short* pA = smem + (ks & 1) * 16384;
        const short* pB = pA + 8192;
#pragma unroll
        for (int h = 0; h < 2; ++h) {
            short8 af[4], bf[4];
#pragma unroll
            for (int t = 0; t < 4; ++t) {
                const int row = wm + t * 16 + fr;
                af[t] = *(const short8*)&pA[row * 64 + (((h * 4 + q) ^ (row & 7)) * 8)];
            }
#pragma unroll
            for (int t = 0; t < 4; ++t) {
                const int row = wn + t * 16 + fr;
                bf[t] = *(const short8*)&pB[row * 64 + (((h * 4 + q) ^ (row & 7)) * 8)];
            }
#pragma unroll
            for (int mt = 0; mt < 4; ++mt)
#pragma unroll
                for (int nt = 0; nt < 4; ++nt)
                    acc[mt][nt] = __builtin_amdgcn_mfma_f32_16x16x32_bf16(
                        af[mt], bf[nt], acc[mt][nt], 0, 0, 0);
        }
        __syncthreads();   // drains prefetch (vmcnt 0) + readers done -> swap safe
    }

    // ---- epilogue: wave-private fp32 LDS stage -> coalesced short8 stores ----
    float* eps = (float*)smem + wave * (16 * 68);
    const int col = lane & 15;
    const int rb  = (lane >> 4) * 4;
#pragma unroll
    for (int mt = 0; mt < 4; ++mt) {
        const int gr0 = tileM + wm + mt * 16;
        const int gc0 = tileN + wn;
#pragma unroll
        for (int nt = 0; nt < 4; ++nt) {
            float bv = 0.0f;
            if constexpr (EPI != 3) { if (p.bias) bv = p.bias[gc0 + nt * 16 + col]; }
#pragma unroll
            for (int r = 0; r < 4; ++r) {
                float v = acc[mt][nt][r] + bv;
                if constexpr (EPI == 1) v = 0.5f * v * (1.0f + erff(v * 0.70710678118654752f));
                eps[(rb + r) * 68 + nt * 16 + col] = v;
            }
        }
        // wave-private region; DS ops in-order per wave — no barrier needed
#pragma unroll
        for (int j = 0; j < 2; ++j) {
            const int r  = (lane >> 3) + 8 * j;
            const int cb = (lane & 7) * 8;
            const floatx4 f0 = *(const floatx4*)&eps[r * 68 + cb];
            const floatx4 f1 = *(const floatx4*)&eps[r * 68 + cb + 4];
            const int gr = gr0 + r;
            if (gr >= p.M) continue;
            float rbv = 0.0f;
            if constexpr (EPI == 3) rbv = p.bias[gr];
            short8 o;
            if constexpr (EPI == 2) {
                const short8 rr = *(const short8*)&p.R[(long long)gr * p.ldr + gc0 + cb];
#pragma unroll
                for (int i = 0; i < 4; ++i) {
                    o[i]     = f2s(f0[i] + s2f(rr[i]));
                    o[4 + i] = f2s(f1[i] + s2f(rr[4 + i]));
                }
            } else {
#pragma unroll
                for (int i = 0; i < 4; ++i) {
                    o[i]     = f2s(f0[i] + rbv);
                    o[4 + i] = f2s(f1[i] + rbv);
                }
            }
            *(short8*)&C[(long long)gr * p.ldc + gc0 + cb] = o;
        }
    }
}

// Combined QK (EPI 0) + VT (EPI 3) dispatch: flat grid, chunked, block branch.
// QK: 50 bx x 12 by (by-fast). VT: 32 z x 6 bx x 2 by (z-major).
__global__ __launch_bounds__(256) void qkvt_k(GP qk, GP vt, int nQK)
{
    __shared__ short smem[32768];
    const int pos = xcd_chunk((int)blockIdx.x, (int)gridDim.x);
    if (pos < nQK) {
        gemm128_body<0>(smem, qk, pos / 12, pos % 12, 0);
    } else {
        const int i2 = pos - nQK;
        gemm128_body<3>(smem, vt, (i2 % 12) >> 1, i2 & 1, i2 / 12);
    }
}

// ---------------------------------------------------------------------------
// gemm64d: 64(M)x128(N) tile, BK=64, SAME dbuf pipeline + 8-slot swizzle as
// gemm128 but half the M-tile: 48 KB LDS -> 3 blk/CU, and ~2x the grid for
// the M=6304 GEMMs (594 blocks vs 300) and PV (768 vs 384). Restores
// inter-block latency hiding (G1) that 300-block 128^2 grids lack (1.17/CU).
// 4 waves 2x2: each wave 32x64 = acc[2][4] (32 VGPR).
// ---------------------------------------------------------------------------
template<int EPI>
DEV void gemm64d_body(short* smem, const GP p, int bx, int by, int bz)
{
    const short* A  = p.A  + (long long)bz * p.zA;
    const short* Bt = p.Bt + (long long)bz * p.zB;
    short* C        = p.C  + (long long)bz * p.zC;

    const int tid   = threadIdx.x;
    const int lane  = tid & 63;
    const int wave  = tid >> 6;
    const int tileM = bx * 64;
    const int tileN = by * 128;
    const int wm    = (wave & 1) * 32;
    const int wn    = (wave >> 1) * 64;

    floatx4 acc[2][4];
#pragma unroll
    for (int mt = 0; mt < 2; ++mt)
#pragma unroll
        for (int nt = 0; nt < 4; ++nt)
            acc[mt][nt] = (floatx4){0.f, 0.f, 0.f, 0.f};

    // per buffer 12288 shorts: A [0,4096) (64x64), B [4096,12288) (128x64).
    // chunk c = i*256+tid: row = i*32 + (tid>>3); row&7 = (tid>>3)&7 invariant
    // -> thread-constant swizzled global source (rule #21 involution).
    const int arow = tid >> 3;
    const int asl  = ((tid & 7) ^ (arow & 7)) * 8;
    const short* gA = A  + (long long)(tileM + arow) * p.lda + asl;
    const short* gB = Bt + (long long)(tileN + arow) * p.ldb + asl;
    const long long stA = 32LL * p.lda;
    const long long stB = 32LL * p.ldb;

    auto stage = [&](int buf, int k0) {
        short* dst = smem + buf * 12288;
#pragma unroll
        for (int i = 0; i < 2; ++i)     // A: 64 rows
            async_copy16(gA + i * stA + k0, &dst[(i * 256 + tid) * 8]);
#pragma unroll
        for (int i = 0; i < 4; ++i)     // B: 128 rows
            async_copy16(gB + i * stB + k0, &dst[4096 + (i * 256 + tid) * 8]);
    };

    const int nK = p.K >> 6;
    stage(0, 0);
    __syncthreads();

    const int fr = lane & 15;
    const int q  = lane >> 4;
    for (int ks = 0; ks < nK; ++ks) {
        if (ks + 1 < nK) stage((ks + 1) & 1, (ks + 1) << 6);   // prefetch overlaps compute
        const short* pA = smem + (ks & 1) * 12288;
        const short* pB = pA + 4096;
#pragma unroll
        for (int h = 0; h < 2; ++h) {
            short8 af[2], bf[4];
#pragma unroll
            for (int t = 0; t < 2; ++t) {
                const int row = wm + t * 16 + fr;
                af[t] = *(const short8*)&pA[row * 64 + (((h * 4 + q) ^ (row & 7)) * 8)];
            }
#pragma unroll
            for (int t = 0; t < 4; ++t) {
                const int row = wn + t * 16 + fr;
                bf[t] = *(const short8*)&pB[row * 64 + (((h * 4 + q) ^ (row & 7)) * 8)];
            }
#pragma unroll
            for (int mt = 0; mt < 2; ++mt)
#pragma unroll
                for (int nt = 0; nt < 4; ++nt)
                    acc[mt][nt] = __builtin_amdgcn_mfma_f32_16x16x32_bf16(
                        af[mt], bf[nt], acc[mt][nt], 0, 0, 0);
        }
        __syncthreads();
    }

    // ---- epilogue: wave-private fp32 LDS stage -> coalesced short8 stores ----
    float* eps = (float*)smem + wave * (16 * 68);
    const int col = lane & 15;
    const int rb  = (lane >> 4) * 4;
#pragma unroll
    for (int mt = 0; mt < 2; ++mt) {
        const int gr0 = tileM + wm + mt * 16;
        const int gc0 = tileN + wn;
#pragma unroll
        for (int nt = 0; nt < 4; ++nt) {
            float bv = 0.0f;
            if (p.bias) bv = p.bias[gc0 + nt * 16 + col];
#pragma unroll
            for (int r = 0; r < 4; ++r) {
                float v = acc[mt][nt][r] + bv;
                if constexpr (EPI == 1) v = 0.5f * v * (1.0f + erff(v * 0.70710678118654752f));
                eps[(rb + r) * 68 + nt * 16 + col] = v;
            }
        }
#pragma unroll
        for (int j = 0; j < 2; ++j) {
            const int r  = (lane >> 3) + 8 * j;
            const int cb = (lane & 7) * 8;
            const floatx4 f0 = *(const floatx4*)&eps[r * 68 + cb];
            const floatx4 f1 = *(const floatx4*)&eps[r * 68 + cb + 4];
            const int gr = gr0 + r;
            if (gr >= p.M) continue;
            short8 o;
            if constexpr (EPI == 2) {
                const short8 rr = *(const short8*)&p.R[(long long)gr * p.ldr + gc0 + cb];
#pragma unroll
                for (int i = 0; i < 4; ++i) {
                    o[i]     = f2s(f0[i] + s2f(rr[i]));
                    o[4 + i] = f2s(f1[i] + s2f(rr[4 + i]));
                }
            } else {
#pragma unroll
                for (int i = 0; i < 4; ++i) {
                    o[i]     = f2s(f0[i]);
                    o[4 + i] = f2s(f1[i]);
                }
            }
            *(short8*)&C[(long long)gr * p.ldc + gc0 + cb] = o;
        }
    }
}

// flat-grid gemm64d with XCD-chunked decode: pos = z*perZ + bx*nBy + by
template<int EPI>
__global__ __launch_bounds__(256) void gemm64d_k(GP p, int nBy, int perZ)
{
    __shared__ short smem[24576];
    const int pos = xcd_chunk((int)blockIdx.x, (int)gridDim.x);
    const int z   = pos / perZ;
    const int rem = pos % perZ;
    gemm64d_body<EPI>(smem, p, rem / nBy, rem % nBy, z);
}

// ---------------------------------------------------------------------------
// Transpose-convert: out_bf16[z][n][k] = f2s(in_f32[z][k][n]). K,N mult of 32.
// ---------------------------------------------------------------------------
__global__ void tconv_k(const float* __restrict__ in, short* __restrict__ out,
                        int K, int N, long long inZ, long long outZ)
{
    __shared__ float t[32][33];
    in  += (long long)blockIdx.z * inZ;
    out += (long long)blockIdx.z * outZ;
    const int n0 = blockIdx.x * 32, k0 = blockIdx.y * 32;
    const int tx = threadIdx.x, ty = threadIdx.y;
#pragma unroll
    for (int i = 0; i < 4; ++i)
        t[ty + i * 8][tx] = in[(long long)(k0 + ty + i * 8) * N + n0 + tx];
    __syncthreads();
#pragma unroll
    for (int i = 0; i < 4; ++i)
        out[(long long)(n0 + ty + i * 8) * K + k0 + tx] = f2s(t[tx][ty + i * 8]);
}

// x fp32 -> bf16, 4 elems/thread (G13)
__global__ __launch_bounds__(256) void cvtx4_k(const float* __restrict__ x,
                                               short* __restrict__ xb, int n4)
{
    const int i = blockIdx.x * 256 + threadIdx.x;
    if (i >= n4) return;
    const floatx4 v = *(const floatx4*)&x[i * 4];
    short4v o;
#pragma unroll
    for (int e = 0; e < 4; ++e) o[e] = f2s(v[e]);
    *(short4v*)&xb[i * 4] = o;
}

// concat per-layer q/k biases -> [12][1536] fp32
__global__ __launch_bounds__(256) void bqk_k(
    const float* __restrict__ bq, const float* __restrict__ bk,
    float* __restrict__ out)
{
    const int i = blockIdx.x * 256 + threadIdx.x;
    if (i >= 12 * 1536) return;
    const int l = i / 1536, j = i % 1536;
    out[i] = (j < 768) ? bq[l * 768 + j] : bk[l * 768 + j - 768];
}

// ---------------------------------------------------------------------------
// assemble: H[b][t][d] = (t==0 ? cls[d] : P[b*196+t-1][d]) + pos[t][d]
// 4 elems/thread (d-contiguous; t uniform within a chunk).
// ---------------------------------------------------------------------------
__global__ __launch_bounds__(256) void assemble4_k(
    const short* __restrict__ P, const float* __restrict__ cls,
    const float* __restrict__ pos, short* __restrict__ H)
{
    const int c = blockIdx.x * 256 + threadIdx.x;   // chunk of 4; 32*197*192 total
    if (c >= 32 * 197 * 192) return;
    const int d4 = c % 192;
    const int t  = (c / 192) % 197;
    const long long b = c / (192 * 197);
    const floatx4 pv = *(const floatx4*)&pos[t * 768 + d4 * 4];
    float o[4];
    if (t == 0) {
        const floatx4 cv = *(const floatx4*)&cls[d4 * 4];
#pragma unroll
        for (int e = 0; e < 4; ++e) o[e] = cv[e] + pv[e];
    } else {
        const short4v pc = *(const short4v*)&P[(b * 196 + t - 1) * 768 + d4 * 4];
#pragma unroll
        for (int e = 0; e < 4; ++e) o[e] = s2f(pc[e]) + pv[e];
    }
    short4v ov;
#pragma unroll
    for (int e = 0; e < 4; ++e) ov[e] = f2s(o[e]);
    *(short4v*)&H[((b * 197 + t) * 768) + d4 * 4] = ov;
}

// ---------------------------------------------------------------------------
// wave-per-row softmax on padded S (4 rows/block, 1576 blocks).
// Row r = b*197+t lives at S[(b*256+t)*256]. Lane loads cols [4*lane,4*lane+4):
// one short4, masks cols >= 197, shuffle-reduce max+sum, writes full 256 cols
// (pad cols = 0 so PV's K=256 pad stays exact).
// ---------------------------------------------------------------------------
__global__ __launch_bounds__(256) void softmaxw_k(short* __restrict__ S, float scale)
{
    const int row  = blockIdx.x * 4 + (threadIdx.x >> 6);
    const int lane = threadIdx.x & 63;
    if (row >= 32 * 197) return;
    const int b = row / 197, t = row % 197;
    short* s = S + ((long long)b * 256 + t) * 256;
    const int c0 = lane * 4;

    const short4v v = *(const short4v*)&s[c0];
    float f[4], mx = -1e30f;
#pragma unroll
    for (int e = 0; e < 4; ++e) {
        f[e] = (c0 + e < 197) ? s2f(v[e]) * scale : -1e30f;
        mx = fmaxf(mx, f[e]);
    }
#pragma unroll
    for (int m = 1; m < 64; m <<= 1) mx = fmaxf(mx, __shfl_xor(mx, m, 64));
    float e4[4], sum = 0.0f;
#pragma unroll
    for (int e = 0; e < 4; ++e) {
        e4[e] = (c0 + e < 197) ? expf(f[e] - mx) : 0.0f;
        sum += e4[e];
    }
#pragma unroll
    for (int m = 1; m < 64; m <<= 1) sum += __shfl_xor(sum, m, 64);
    const float inv = 1.0f / sum;
    short4v o;
#pragma unroll
    for (int e = 0; e < 4; ++e) o[e] = f2s(e4[e] * inv);
    *(short4v*)&s[c0] = o;
}

// ---------------------------------------------------------------------------
// wave-per-row LayerNorm over 768 (shuffle reduce). 4 rows/block.
// Vectorized: 3 x short4 loads / stores per lane (G13).
// ---------------------------------------------------------------------------
__global__ __launch_bounds__(256) void lnw_k(
    const short* __restrict__ X, long long xs,
    short* __restrict__ Y, long long ys,
    const float* __restrict__ g, const float* __restrict__ be, int nrows)
{
    const int row  = blockIdx.x * 4 + (threadIdx.x >> 6);
    const int lane = threadIdx.x & 63;
    if (row >= nrows) return;
    const short* x = X + (long long)row * xs;
    short* y = Y + (long long)row * ys;

    float v[12], s = 0.0f, sq = 0.0f;
#pragma unroll
    for (int j = 0; j < 3; ++j) {
        const short4v t4 = *(const short4v*)&x[(lane + 64 * j) * 4];
#pragma unroll
        for (int e = 0; e < 4; ++e) {
            const float t = s2f(t4[e]);
            v[j * 4 + e] = t; s += t; sq += t * t;
        }
    }
#pragma unroll
    for (int m = 1; m < 64; m <<= 1) {
        s  += __shfl_xor(s,  m, 64);
        sq += __shfl_xor(sq, m, 64);
    }
    const float mean = s * (1.0f / 768.0f);
    const float var  = sq * (1.0f / 768.0f) - mean * mean;
    const float rs   = rsqrtf(var + 1e-5f);
#pragma unroll
    for (int j = 0; j < 3; ++j) {
        const int d0 = (lane + 64 * j) * 4;
        const floatx4 gv = *(const floatx4*)&g[d0];
        const floatx4 bv = *(const floatx4*)&be[d0];
        short4v o;
#pragma unroll
        for (int e = 0; e < 4; ++e)
            o[e] = f2s((v[j * 4 + e] - mean) * rs * gv[e] + bv[e]);
        *(short4v*)&y[d0] = o;
    }
}

// ---------------------------------------------------------------------------
// head3: out[b][c] = hc[b].W[:,c] + hb[c]; split-k x4 + LDS reduce.
// grid (16, 32); block 256 = 64 cols x 4 k-slices. fp32 W, fp32 out.
// ---------------------------------------------------------------------------
__global__ __launch_bounds__(256) void head3_k(
    const short* __restrict__ hc, const float* __restrict__ W,
    const float* __restrict__ hb, float* __restrict__ out)
{
    const int b  = blockIdx.y;
    const int cc = threadIdx.x & 63;
    const int ks = threadIdx.x >> 6;
    const int c  = blockIdx.x * 64 + cc;
    __shared__ float h[768];
    __shared__ float red[4][64];
    for (int i = threadIdx.x; i < 768; i += 256) h[i] = s2f(hc[b * 768 + i]);
    __syncthreads();
    float acc = 0.0f;
    if (c < 1000) {
        const int k0 = ks * 192;
        for (int k = k0; k < k0 + 192; ++k) acc += h[k] * W[k * 1000 + c];
    }
    red[ks][cc] = acc;
    __syncthreads();
    if (ks == 0 && c < 1000)
        out[b * 1000 + c] = red[0][cc] + red[1][cc] + red[2][cc] + red[3][cc] + hb[c];
}

// ---------------------------------------------------------------------------
extern "C" void kernel_launch(void* const* d_in, const int* in_sizes, int n_in,
                              void* d_out, int out_size, void* d_ws, size_t ws_size,
                              hipStream_t stream)
{
    const float* x     = (const float*)d_in[0];
    const float* cls   = (const float*)d_in[1];
    const float* emb_w = (const float*)d_in[2];
    const float* emb_b = (const float*)d_in[3];
    const float* pos   = (const float*)d_in[4];
    const float* Wq    = (const float*)d_in[5];
    const float* bq    = (const float*)d_in[6];
    const float* Wk    = (const float*)d_in[7];
    const float* bk    = (const float*)d_in[8];
    const float* Wv    = (const float*)d_in[9];
    const float* bv    = (const float*)d_in[10];
    const float* Wo    = (const float*)d_in[11];
    const float* bo    = (const float*)d_in[12];
    const float* g1    = (const float*)d_in[13];
    const float* be1   = (const float*)d_in[14];
    const float* W1    = (const float*)d_in[15];
    const float* b1    = (const float*)d_in[16];
    const float* W2    = (const float*)d_in[17];
    const float* b2    = (const float*)d_in[18];
    const float* g2    = (const float*)d_in[19];
    const float* be2   = (const float*)d_in[20];
    const float* fg    = (const float*)d_in[21];
    const float* fb    = (const float*)d_in[22];
    const float* hw    = (const float*)d_in[23];
    const float* hb    = (const float*)d_in[24];

    char* ws = (char*)d_ws;
    long long o = 0;
    short* WtQK = (short*)(ws + o); o += 12LL * 1536 * 768 * 2;
    short* WtV  = (short*)(ws + o); o += 12LL * 768 * 768 * 2;
    short* WtO  = (short*)(ws + o); o += 12LL * 768 * 768 * 2;
    short* Wt1  = (short*)(ws + o); o += 12LL * 768 * 768 * 2;
    short* Wt2  = (short*)(ws + o); o += 12LL * 768 * 768 * 2;
    short* embT = (short*)(ws + o); o += 768LL * 256 * 2;
    short* H    = (short*)(ws + o); o += 6400LL * 768 * 2;
    short* QKVb = (short*)(ws + o); o += 6400LL * 1536 * 2;
    short* AO   = (short*)(ws + o); o += 6400LL * 768 * 2;
    short* VT   = (short*)(ws + o); o += 32LL * 768 * 256 * 2;
    short* T1   = VT;                                  // alias (disjoint in time)
    short* S    = (short*)(ws + o); o += 32LL * 256 * 256 * 2;
    short* xb   = S;                                   // alias (disjoint in time)
    short* hc   = (short*)(ws + o); o += 64LL * 768 * 2;
    float* bqk  = (float*)(ws + o); o += 12LL * 1536 * 4;

    const dim3 blk(256);
    const dim3 tblk(32, 8);
    const float scale = 0.03608439182435161f;  // 768^-0.5
    const long long sH  = 197LL * 768;
    const long long sQK = 197LL * 1536;
    const long long sS  = 256LL * 256;
    const long long sVT = 768LL * 256;

    // ---- prep ----
    tconv_k<<<dim3(24, 8, 1),   tblk, 0, stream>>>(emb_w, embT, 256, 768, 0, 0);
    tconv_k<<<dim3(24, 24, 12), tblk, 0, stream>>>(Wq, WtQK,             768, 768, 589824, 1536LL * 768);
    tconv_k<<<dim3(24, 24, 12), tblk, 0, stream>>>(Wk, WtQK + 768 * 768, 768, 768, 589824, 1536LL * 768);
    tconv_k<<<dim3(24, 24, 12), tblk, 0, stream>>>(Wv, WtV, 768, 768, 589824, 589824);
    tconv_k<<<dim3(24, 24, 12), tblk, 0, stream>>>(Wo, WtO, 768, 768, 589824, 589824);
    tconv_k<<<dim3(24, 24, 12), tblk, 0, stream>>>(W1, Wt1, 768, 768, 589824, 589824);
    tconv_k<<<dim3(24, 24, 12), tblk, 0, stream>>>(W2, Wt2, 768, 768, 589824, 589824);
    cvtx4_k<<<dim3(1568), blk, 0, stream>>>(x, xb, 6272 * 64);
    bqk_k<<<dim3(72), blk, 0, stream>>>(bq, bk, bqk);

    // ---- patch embed (98bx x 6by = 588 blocks) + assemble ----
    {
        GP p = { xb, 0, 256, embT, 0, 256, emb_b, nullptr, 0, T1, 0, 768, 6272, 768, 256 };
        gemm64d_k<0><<<dim3(588), blk, 0, stream>>>(p, 6, 588);
    }
    assemble4_k<<<dim3((32 * 197 * 192 + 255) / 256), blk, 0, stream>>>(T1, cls, pos, H);

    for (int l = 0; l < 12; ++l) {
        const long long w1o = (long long)l * 589824;
        const long long vo  = (long long)l * 768;
        // QK [6304][1536] (50x12 @128^2) + VT[b][d][t] (32x6x2) in ONE dispatch
        {
            GP qk = { H, 0, 768, WtQK + (long long)l * 1536 * 768, 0, 768,
                      bqk + l * 1536, nullptr, 0, QKVb, 0, 1536, 6304, 1536, 768 };
            GP vt = { WtV + w1o, 0, 768, H, sH, 768, bv + vo,
                      nullptr, 0, VT, sVT, 256, 768, 256, 768 };
            qkvt_k<<<dim3(600 + 384), blk, 0, stream>>>(qk, vt, 600);
        }
        // S[b] = Q[b] @ K[b]^T  [197(pad256)][256]: 4bx x 2by x 32z = 256 blocks
        {
            GP p = { QKVb, sQK, 1536, QKVb + 768, sQK, 1536, nullptr,
                     nullptr, 0, S, sS, 256, 197, 256, 768 };
            gemm64d_k<0><<<dim3(256), blk, 0, stream>>>(p, 2, 8);
        }
        softmaxw_k<<<dim3(1576), blk, 0, stream>>>(S, scale);
        // AO[b] = P[b] @ VT[b]^T  (K=256): 4bx x 6by x 32z = 768 blocks
        {
            GP p = { S, sS, 256, VT, sVT, 256, nullptr,
                     nullptr, 0, AO, sH, 768, 197, 768, 256 };
            gemm64d_k<0><<<dim3(768), blk, 0, stream>>>(p, 6, 24);
        }
        // T1 = AO @ Wo + bo + H ; H = LN(T1)   (99bx x 6by = 594, by-fast)
        {
            GP p = { AO, 0, 768, WtO + w1o, 0, 768, bo + vo, H, 768,
                     T1, 0, 768, 6304, 768, 768 };
            gemm64d_k<2><<<dim3(594), blk, 0, stream>>>(p, 6, 594);
        }
        lnw_k<<<dim3(1576), blk, 0, stream>>>(T1, 768, H, 768, g1 + vo, be1 + vo, 6304);
        // T1 = gelu(H @ W1 + b1) ; AO = T1 @ W2 + b2 + H ; H = LN(AO)
        {
            GP p = { H, 0, 768, Wt1 + w1o, 0, 768, b1 + vo, nullptr, 0,
                     T1, 0, 768, 6304, 768, 768 };
            gemm64d_k<1><<<dim3(594), blk, 0, stream>>>(p, 6, 594);
        }
        {
            GP p = { T1, 0, 768, Wt2 + w1o, 0, 768, b2 + vo, H, 768,
                     AO, 0, 768, 6304, 768, 768 };
            gemm64d_k<2><<<dim3(594), blk, 0, stream>>>(p, 6, 594);
        }
        lnw_k<<<dim3(1576), blk, 0, stream>>>(AO, 768, H, 768, g2 + vo, be2 + vo, 6304);
    }

    // final LN on cls tokens (stride 197*768) + head
    lnw_k<<<dim3(8), blk, 0, stream>>>(H, sH, hc, 768, fg, fb, 32);
    head3_k<<<dim3(16, 32), blk, 0, stream>>>(hc, hw, hb, (float*)d_out);
}